// Round 6
// baseline (178.499 us; speedup 1.0000x reference)
//
#include <hip/hip_runtime.h>

typedef _Float16 half_t;
typedef _Float16 v8h __attribute__((ext_vector_type(8)));
typedef float v4f __attribute__((ext_vector_type(4)));

#define XTP 40   // xt LDS row pitch (halves): 32 data + 8 pad (16B-aligned rows)

typedef __attribute__((address_space(3))) unsigned int lds_u32;
typedef const __attribute__((address_space(1))) unsigned int glb_u32;

// async 16B/lane global->LDS DMA: lds dest = l + lane*16 (HW), src = g + lane*16
__device__ __forceinline__ void dma16(const half_t* g, half_t* l, int lane) {
  __builtin_amdgcn_global_load_lds((glb_u32*)(g + lane * 8), (lds_u32*)(l), 16, 0, 0);
}

// raw waitcnt: vmcnt(N), lgkmcnt/expcnt = no-wait  (gfx9 encoding)
#define WAITVM(N) __builtin_amdgcn_s_waitcnt(0xF70 | (N))
#define SCHED0()  __builtin_amdgcn_sched_barrier(0)

// ============ prep: x (B,32,16) f32 -> xt (B,16,32) f16 (transpose f<->e) ============
__global__ __launch_bounds__(256) void prep_x(const float* __restrict__ x, half_t* __restrict__ xt) {
  __shared__ half_t t[8 * 512];
  const int tid = threadIdx.x;
  const size_t b0 = (size_t)blockIdx.x * 8;
#pragma unroll
  for (int i = 0; i < 4; ++i) {
    int idx = (i * 256 + tid) * 4;           // element index within 8 batch rows
    float4 v = *(const float4*)(x + b0 * 512 + idx);
    int e = idx & 15, f = (idx >> 4) & 31, b = idx >> 9;
    half_t* d = t + b * 512 + f;             // t layout [b][e*32+f]
    d[(e + 0) * 32] = (half_t)v.x;
    d[(e + 1) * 32] = (half_t)v.y;
    d[(e + 2) * 32] = (half_t)v.z;
    d[(e + 3) * 32] = (half_t)v.w;
  }
  __syncthreads();
#pragma unroll
  for (int i = 0; i < 2; ++i) {
    int c = i * 256 + tid;
    *(uint4*)(xt + b0 * 512 + c * 8) = *(const uint4*)(t + c * 8);
  }
}

// ===== prep: W (128,K) f32 -> f16 chunked [K/8][128][8]: chunk (k>>3)*128+o = W[o][k..k+8) =====
__global__ __launch_bounds__(256) void prep_w(const float* __restrict__ src, half_t* __restrict__ dst,
                                              int ktot, int nchunk) {
  int i = blockIdx.x * 256 + threadIdx.x;
  if (i >= nchunk) return;
  int o = i & 127, k8 = i >> 7;
  const float* s = src + (size_t)o * ktot + k8 * 8;
  float4 f0 = *(const float4*)s;
  float4 f1 = *(const float4*)(s + 4);
  union { half_t h[8]; uint4 u; } pk;
  pk.h[0] = (half_t)f0.x; pk.h[1] = (half_t)f0.y; pk.h[2] = (half_t)f0.z; pk.h[3] = (half_t)f0.w;
  pk.h[4] = (half_t)f1.x; pk.h[5] = (half_t)f1.y; pk.h[6] = (half_t)f1.z; pk.h[7] = (half_t)f1.w;
  *(uint4*)(dst + (size_t)i * 8) = pk.u;
}

// ============ one CIN layer: Y = relu(W @ Z + b), Z built on the fly ============
// Block: 512 thr (8 waves), tile M=128(o) x N=256(16 batch x 16 e). Wave tile 64x64.
// Grid = 256 = 1 block/CU: halves chip-wide W re-reads vs N=128 (the R2-R5 invariant wall:
// L2 same-line serialization, ~310-560 B/cyc/XCD W delivery regardless of mechanism/depth).
// W staged via global_load_lds DMA into a 4-slab ring (1 dma16/wave/step), depth 3,
// raw s_waitcnt vmcnt(N)+s_barrier per step. h fragments register-resident.
template <int G, int KTOT, int KEEP, int OUT_BASE, bool H_OUT, bool H_IS_X>
__global__ __launch_bounds__(512, 1) void cin_layer(const half_t* __restrict__ xt,
                                                    const half_t* __restrict__ hin,
                                                    const half_t* __restrict__ wgt,
                                                    const float* __restrict__ bias,
                                                    half_t* __restrict__ hout,
                                                    float* __restrict__ out) {
  constexpr int NS = KTOT / 32;            // K-steps of 32
  constexpr int SPO = (G == 64) ? 16 : 8;  // steps per f-octet (SPO % 4 == 0)
  constexpr int NOCT = NS / SPO;           // 4 for both layer shapes
  constexpr int NSEL = (G == 64) ? 2 : 1;
  __shared__ __align__(16) half_t xt_lds[256 * XTP];   // 16 batch x 16 e rows
  __shared__ __align__(16) half_t w_lds[4 * 4096];     // 4-slab W ring (8KB each)
  __shared__ float bias_lds[128];

  const int tid = threadIdx.x;
  const int lane = tid & 63;
  const int wv = tid >> 6;                 // 0..7
  const size_t b0 = (size_t)blockIdx.x * 16;
  const int phase = (blockIdx.x >> 3) & 3; // co-XCD blocks start on different octets

  // ---- stage xt: 256 rows (b,e) x 32 halves (each thread: one 16-half chunk) ----
  {
    const int r = tid >> 1, c = (tid & 1) * 16;
    const half_t* src = xt + b0 * 512 + r * 32 + c;
    uint4 q0 = *(const uint4*)(src);
    uint4 q1 = *(const uint4*)(src + 8);
    *(uint4*)(xt_lds + r * XTP + c) = q0;
    *(uint4*)(xt_lds + r * XTP + c + 8) = q1;
  }
  if (tid < 128) bias_lds[tid] = bias[tid];

  const int wm = (wv & 1) * 64;        // o offset of wave
  const int wb = (wv >> 1) * 4;        // batch offset of wave within block (0,4,8,12)
  const int col = lane & 15;           // = e (A/B/C intra-tile index)
  const int kq = lane >> 4;            // k-quad (fixed per lane)

  int lrow[4];
#pragma unroll
  for (int ni = 0; ni < 4; ++ni) lrow[ni] = (wb + ni) * 16 + col;

  // ---- h fragments: register-resident for the whole K-loop ----
  v8h hreg[4][NSEL];
  if (!H_IS_X) {
#pragma unroll
    for (int ni = 0; ni < 4; ++ni) {
      const half_t* hp = hin + ((b0 + wb + ni) * 16 + col) * 64 + kq * 8;
      hreg[ni][0] = *(const v8h*)(hp);
      if (NSEL > 1) hreg[ni][NSEL - 1] = *(const v8h*)(hp + 32);
    }
  }

  // ---- prologue: DMA pipeline slabs 0..2 (rotated), 1 dma16 (1KB) per wave per slab ----
#pragma unroll
  for (int p = 0; p < 3; ++p) {
    const half_t* wsrc = wgt + (size_t)(phase * SPO + p) * 4096;   // p < SPO always
    half_t* pb = w_lds + p * 4096;
    dma16(wsrc + wv * 512, pb + wv * 512, lane);
  }

  __syncthreads();   // xt+bias visible; DMA 0..2 drained (one full drain, only here)

  if (H_IS_X) {
#pragma unroll
    for (int ni = 0; ni < 4; ++ni)
      hreg[ni][0] = *(const v8h*)(xt_lds + lrow[ni] * XTP + kq * 8);
  }

  v4f acc[4][4] = {};

  // ---- main octets (all but last) ----
#pragma unroll 1
  for (int oi = 0; oi < NOCT - 1; ++oi) {
    const int oct_a = (oi + phase) & 3;           // octet being computed
    const int next_a = (oi + 1 + phase) & 3;      // octet of cross-boundary prefetch
    v8h xv[4];
#pragma unroll
    for (int ni = 0; ni < 4; ++ni)
      xv[ni] = *(const v8h*)(xt_lds + lrow[ni] * XTP + oct_a * 8);
#pragma unroll
    for (int t = 0; t < SPO; ++t) {
      SCHED0(); WAITVM(2); __builtin_amdgcn_s_barrier(); SCHED0();
      {  // prefetch slab at pipeline distance +3
        const int tp = t + 3;
        const half_t* wsrc = (tp < SPO)
            ? wgt + (size_t)(oct_a * SPO + tp) * 4096
            : wgt + (size_t)(next_a * SPO + (tp - SPO)) * 4096;
        half_t* pb = w_lds + (tp & 3) * 4096;     // (oi*SPO + tp) & 3 == tp & 3 (SPO % 4 == 0)
        dma16(wsrc + wv * 512, pb + wv * 512, lane);
      }
      const half_t* rb = w_lds + (t & 3) * 4096;
      const int j = (G == 64) ? (t >> 1) : t;
      const int sel = (G == 64) ? (t & 1) : 0;
      v8h a[4], bfr[4];
#pragma unroll
      for (int mi = 0; mi < 4; ++mi)
        a[mi] = *(const v8h*)(rb + (kq * 128 + wm + mi * 16 + col) * 8);
#pragma unroll
      for (int ni = 0; ni < 4; ++ni)
        bfr[ni] = hreg[ni][sel] * xv[ni][j];
#pragma unroll
      for (int mi = 0; mi < 4; ++mi)
#pragma unroll
        for (int ni = 0; ni < 4; ++ni)
          acc[mi][ni] = __builtin_amdgcn_mfma_f32_16x16x32_f16(a[mi], bfr[ni], acc[mi][ni], 0, 0, 0);
    }
  }

  // ---- final octet (peeled: pipeline tail waits) ----
  {
    const int oct_a = (NOCT - 1 + phase) & 3;
    v8h xv[4];
#pragma unroll
    for (int ni = 0; ni < 4; ++ni)
      xv[ni] = *(const v8h*)(xt_lds + lrow[ni] * XTP + oct_a * 8);
#pragma unroll
    for (int t = 0; t < SPO; ++t) {
      SCHED0();
      if (t < SPO - 2) { WAITVM(2); } else if (t == SPO - 2) { WAITVM(1); } else { WAITVM(0); }
      __builtin_amdgcn_s_barrier(); SCHED0();
      if (t + 3 < SPO) {
        const int tp = t + 3;
        const half_t* wsrc = wgt + (size_t)(oct_a * SPO + tp) * 4096;
        half_t* pb = w_lds + (tp & 3) * 4096;
        dma16(wsrc + wv * 512, pb + wv * 512, lane);
      }
      const half_t* rb = w_lds + (t & 3) * 4096;
      const int j = (G == 64) ? (t >> 1) : t;
      const int sel = (G == 64) ? (t & 1) : 0;
      v8h a[4], bfr[4];
#pragma unroll
      for (int mi = 0; mi < 4; ++mi)
        a[mi] = *(const v8h*)(rb + (kq * 128 + wm + mi * 16 + col) * 8);
#pragma unroll
      for (int ni = 0; ni < 4; ++ni)
        bfr[ni] = hreg[ni][sel] * xv[ni][j];
#pragma unroll
      for (int mi = 0; mi < 4; ++mi)
#pragma unroll
        for (int ni = 0; ni < 4; ++ni)
          acc[mi][ni] = __builtin_amdgcn_mfma_f32_16x16x32_f16(a[mi], bfr[ni], acc[mi][ni], 0, 0, 0);
    }
  }

  // ---- epilogue: bias + relu; rows>=64 -> h_next; rows<KEEP -> sum_e -> out ----
#pragma unroll
  for (int mi = 0; mi < 4; ++mi) {
    const int o_base = wm + mi * 16 + kq * 4;  // C rows o_base..o_base+3 for this lane
#pragma unroll
    for (int ni = 0; ni < 4; ++ni) {
      const int bb = wb + ni;
      float v[4];
#pragma unroll
      for (int r = 0; r < 4; ++r)
        v[r] = fmaxf(acc[mi][ni][r] + bias_lds[o_base + r], 0.0f);
      if (H_OUT && o_base >= 64) {   // wave-uniform: only wm=64 waves
        union { half_t h[4]; uint2 u; } pk;
#pragma unroll
        for (int r = 0; r < 4; ++r) pk.h[r] = (half_t)v[r];
        *(uint2*)(hout + ((b0 + bb) * 16 + col) * 64 + (o_base - 64)) = pk.u;
      }
      if (o_base < KEEP) {           // wave-uniform
#pragma unroll
        for (int r = 0; r < 4; ++r) {
          float sv = v[r];
          sv += __shfl_xor(sv, 1);
          sv += __shfl_xor(sv, 2);
          sv += __shfl_xor(sv, 4);
          sv += __shfl_xor(sv, 8);   // sum over e (16-lane group)
          if (col == 0) out[(b0 + bb) * 256 + OUT_BASE + o_base + r] = sv;
        }
      }
    }
  }
}

extern "C" void kernel_launch(void* const* d_in, const int* in_sizes, int n_in,
                              void* d_out, int out_size, void* d_ws, size_t ws_size,
                              hipStream_t stream) {
  const float* x  = (const float*)d_in[0];
  const float* W0 = (const float*)d_in[1];
  const float* b0 = (const float*)d_in[2];
  const float* W1 = (const float*)d_in[3];
  const float* b1 = (const float*)d_in[4];
  const float* W2 = (const float*)d_in[5];
  const float* b2 = (const float*)d_in[6];
  float* out = (float*)d_out;
  char* ws = (char*)d_ws;

  half_t* xt  = (half_t*)(ws);                          // 4 MB
  half_t* w0h = (half_t*)(ws + (4u << 20));             // 256 KB
  half_t* w1h = (half_t*)(ws + (4u << 20) + (256u << 10));   // 512 KB
  half_t* w2h = (half_t*)(ws + (4u << 20) + (768u << 10));   // 512 KB
  half_t* h1  = (half_t*)(ws + (4u << 20) + (1280u << 10));  // 8 MB
  half_t* h2  = (half_t*)(ws + (12u << 20) + (1280u << 10)); // 8 MB

  prep_x<<<512, 256, 0, stream>>>(x, xt);
  prep_w<<<64, 256, 0, stream>>>(W0, w0h, 1024, 16384);
  prep_w<<<128, 256, 0, stream>>>(W1, w1h, 2048, 32768);
  prep_w<<<128, 256, 0, stream>>>(W2, w2h, 2048, 32768);

  // layer 0: G=32 (h = x0), keep o<64 -> out ch [0,64), o>=64 -> h1
  cin_layer<32, 1024, 64, 0, true, true><<<256, 512, 0, stream>>>(xt, xt, w0h, b0, h1, out);
  // layer 1: G=64, keep o<64 -> out ch [64,128), o>=64 -> h2
  cin_layer<64, 2048, 64, 64, true, false><<<256, 512, 0, stream>>>(xt, h1, w1h, b1, h2, out);
  // layer 2: G=64, keep all 128 -> out ch [128,256)
  cin_layer<64, 2048, 128, 128, false, false><<<256, 512, 0, stream>>>(xt, h2, w2h, b2, nullptr, out);
}

// Round 7
// 148.729 us; speedup vs baseline: 1.2002x; 1.2002x over previous
//
#include <hip/hip_runtime.h>

typedef _Float16 half_t;
typedef _Float16 v8h __attribute__((ext_vector_type(8)));
typedef float v4f __attribute__((ext_vector_type(4)));

#define XTP 40   // xt LDS row pitch (halves): 32 data + 8 pad
#define HP  72   // h  LDS row pitch (halves): 64 data + 8 pad

typedef __attribute__((address_space(3))) unsigned int lds_u32;
typedef const __attribute__((address_space(1))) unsigned int glb_u32;

// async 16B/lane global->LDS DMA: lds dest = l + lane*16 (HW), src = g + lane*16
__device__ __forceinline__ void dma16(const half_t* g, half_t* l, int lane) {
  __builtin_amdgcn_global_load_lds((glb_u32*)(g + lane * 8), (lds_u32*)(l), 16, 0, 0);
}

// raw waitcnt: vmcnt(N), lgkmcnt/expcnt = no-wait (gfx9 encoding)
#define WAITVM(N) __builtin_amdgcn_s_waitcnt(0xF70 | (N))
#define SCHED0()  __builtin_amdgcn_sched_barrier(0)

// ===== merged W prep: W (128,K) f32 -> f16 chunked [K/8][128][8] for all 3 layers =====
__global__ __launch_bounds__(256) void prep_w_all(const float* __restrict__ W0,
                                                  const float* __restrict__ W1,
                                                  const float* __restrict__ W2,
                                                  half_t* __restrict__ w0h,
                                                  half_t* __restrict__ w1h,
                                                  half_t* __restrict__ w2h) {
  int i = blockIdx.x * 256 + threadIdx.x;         // 0..81919 (wave-uniform segments)
  const float* src; half_t* dst; int ktot; int j;
  if (i < 16384)      { src = W0; dst = w0h; ktot = 1024; j = i; }
  else if (i < 49152) { src = W1; dst = w1h; ktot = 2048; j = i - 16384; }
  else                { src = W2; dst = w2h; ktot = 2048; j = i - 49152; }
  int o = j & 127, k8 = j >> 7;
  const float* s = src + (size_t)o * ktot + k8 * 8;
  float4 f0 = *(const float4*)s;
  float4 f1 = *(const float4*)(s + 4);
  union { half_t h[8]; uint4 u; } pk;
  pk.h[0] = (half_t)f0.x; pk.h[1] = (half_t)f0.y; pk.h[2] = (half_t)f0.z; pk.h[3] = (half_t)f0.w;
  pk.h[4] = (half_t)f1.x; pk.h[5] = (half_t)f1.y; pk.h[6] = (half_t)f1.z; pk.h[7] = (half_t)f1.w;
  *(uint4*)(dst + (size_t)j * 8) = pk.u;
}

// ============ one CIN layer (device): Y = relu(W @ Z + b), Z built on the fly ============
// Wave tile 64(o) x 32(2 batch x 16 e), 8 waves cover M=128 x N=128. R6 K-loop skeleton:
// W via global_load_lds 4-slab ring, depth 3, raw vmcnt(N)+s_barrier per step.
template <int G, int KTOT, int KEEP, int OUT_BASE, bool H_OUT, bool H_IS_X>
__device__ __forceinline__ void layer(const half_t* __restrict__ wgt,
                                      const float* __restrict__ bias,
                                      half_t* __restrict__ xt_lds,
                                      half_t* __restrict__ h_lds,
                                      half_t* __restrict__ w_ring,
                                      float* __restrict__ out,
                                      size_t b0, int tid, int phase) {
  constexpr int SPO = (G == 64) ? 16 : 8;   // steps per f-octet (SPO % 4 == 0)
  constexpr int NOCT = (KTOT / 32) / SPO;   // 4
  constexpr int NSEL = (G == 64) ? 2 : 1;
  const int lane = tid & 63;
  const int wv = tid >> 6;                  // 0..7
  const int wm = (wv & 1) * 64;             // o offset
  const int wb = (wv >> 1) * 2;             // local batch offset (0,2,4,6)
  const int col = lane & 15;                // = e
  const int kq = lane >> 4;                 // k-quad (fixed per lane)

  int lrow[2];
#pragma unroll
  for (int ni = 0; ni < 2; ++ni) lrow[ni] = (wb + ni) * 16 + col;

  __syncthreads();   // prior xt staging / previous layer's h_lds writes visible

  // ---- h fragments: register-resident for the whole K-loop ----
  const half_t* hb = H_IS_X ? xt_lds : h_lds;
  const int hpitch = H_IS_X ? XTP : HP;
  v8h hreg[2][NSEL];
#pragma unroll
  for (int ni = 0; ni < 2; ++ni) {
    const half_t* hp = hb + lrow[ni] * hpitch + kq * 8;
    hreg[ni][0] = *(const v8h*)hp;
    if (NSEL > 1) hreg[ni][NSEL - 1] = *(const v8h*)(hp + 32);
  }

  // ---- prologue: DMA slabs 0..2 (rotated), 1 dma16 (1KB) per wave per slab ----
#pragma unroll
  for (int p = 0; p < 3; ++p) {
    const half_t* wsrc = wgt + (size_t)(phase * SPO + p) * 4096;
    dma16(wsrc + wv * 512, w_ring + p * 4096 + wv * 512, lane);
  }
  __syncthreads();   // DMA 0..2 drained (full drain, only here per layer)

  v4f acc[4][2] = {};

  // ---- main octets (all but last) ----
#pragma unroll 1
  for (int oi = 0; oi < NOCT - 1; ++oi) {
    const int oct_a = (oi + phase) & 3;
    const int next_a = (oi + 1 + phase) & 3;
    v8h xv[2];
#pragma unroll
    for (int ni = 0; ni < 2; ++ni)
      xv[ni] = *(const v8h*)(xt_lds + lrow[ni] * XTP + oct_a * 8);
#pragma unroll
    for (int t = 0; t < SPO; ++t) {
      SCHED0(); WAITVM(2); __builtin_amdgcn_s_barrier(); SCHED0();
      {  // prefetch slab at pipeline distance +3
        const int tp = t + 3;
        const half_t* wsrc = (tp < SPO)
            ? wgt + (size_t)(oct_a * SPO + tp) * 4096
            : wgt + (size_t)(next_a * SPO + (tp - SPO)) * 4096;
        dma16(wsrc + wv * 512, w_ring + (tp & 3) * 4096 + wv * 512, lane);
      }
      const half_t* rb = w_ring + (t & 3) * 4096;
      const int j = (G == 64) ? (t >> 1) : t;
      const int sel = (G == 64) ? (t & 1) : 0;
      v8h a[4], bfr[2];
#pragma unroll
      for (int mi = 0; mi < 4; ++mi)
        a[mi] = *(const v8h*)(rb + (kq * 128 + wm + mi * 16 + col) * 8);
#pragma unroll
      for (int ni = 0; ni < 2; ++ni)
        bfr[ni] = hreg[ni][sel] * xv[ni][j];
#pragma unroll
      for (int mi = 0; mi < 4; ++mi)
#pragma unroll
        for (int ni = 0; ni < 2; ++ni)
          acc[mi][ni] = __builtin_amdgcn_mfma_f32_16x16x32_f16(a[mi], bfr[ni], acc[mi][ni], 0, 0, 0);
    }
  }

  // ---- final octet (peeled pipeline tail) ----
  {
    const int oct_a = (NOCT - 1 + phase) & 3;
    v8h xv[2];
#pragma unroll
    for (int ni = 0; ni < 2; ++ni)
      xv[ni] = *(const v8h*)(xt_lds + lrow[ni] * XTP + oct_a * 8);
#pragma unroll
    for (int t = 0; t < SPO; ++t) {
      SCHED0();
      if (t < SPO - 2) { WAITVM(2); } else if (t == SPO - 2) { WAITVM(1); } else { WAITVM(0); }
      __builtin_amdgcn_s_barrier(); SCHED0();
      if (t + 3 < SPO) {
        const int tp = t + 3;
        const half_t* wsrc = wgt + (size_t)(oct_a * SPO + tp) * 4096;
        dma16(wsrc + wv * 512, w_ring + (tp & 3) * 4096 + wv * 512, lane);
      }
      const half_t* rb = w_ring + (t & 3) * 4096;
      const int j = (G == 64) ? (t >> 1) : t;
      const int sel = (G == 64) ? (t & 1) : 0;
      v8h a[4], bfr[2];
#pragma unroll
      for (int mi = 0; mi < 4; ++mi)
        a[mi] = *(const v8h*)(rb + (kq * 128 + wm + mi * 16 + col) * 8);
#pragma unroll
      for (int ni = 0; ni < 2; ++ni)
        bfr[ni] = hreg[ni][sel] * xv[ni][j];
#pragma unroll
      for (int mi = 0; mi < 4; ++mi)
#pragma unroll
        for (int ni = 0; ni < 2; ++ni)
          acc[mi][ni] = __builtin_amdgcn_mfma_f32_16x16x32_f16(a[mi], bfr[ni], acc[mi][ni], 0, 0, 0);
    }
  }

  // ---- epilogue: bias + relu; rows>=64 -> h_lds (B-layout); rows<KEEP -> sum_e -> out ----
  // Safe without extra barrier: all waves' hreg loads finished >=KTOT/32 barriers ago;
  // h_lds is read by nobody between K-loop start and the next layer's entry sync.
#pragma unroll
  for (int mi = 0; mi < 4; ++mi) {
    const int o_base = wm + mi * 16 + kq * 4;     // C rows o_base..o_base+3
    float4 b4 = *(const float4*)(bias + o_base);
#pragma unroll
    for (int ni = 0; ni < 2; ++ni) {
      const int bb = wb + ni;
      float v[4];
#pragma unroll
      for (int r = 0; r < 4; ++r)
        v[r] = fmaxf(acc[mi][ni][r] + (&b4.x)[r], 0.0f);
      if (H_OUT && o_base >= 64) {                // wave-uniform (== wm==64)
        union { half_t h[4]; uint2 u; } pk;
#pragma unroll
        for (int r = 0; r < 4; ++r) pk.h[r] = (half_t)v[r];
        *(uint2*)(h_lds + (bb * 16 + col) * HP + (o_base - 64)) = pk.u;
      }
      if (o_base < KEEP) {                        // wave-uniform
#pragma unroll
        for (int r = 0; r < 4; ++r) {
          float sv = v[r];
          sv += __shfl_xor(sv, 1);
          sv += __shfl_xor(sv, 2);
          sv += __shfl_xor(sv, 4);
          sv += __shfl_xor(sv, 8);                // sum over e (16-lane group)
          if (col == 0) out[(b0 + bb) * 256 + OUT_BASE + o_base + r] = sv;
        }
      }
    }
  }
}

// ============ fused CIN: all 3 layers, one block = 8 batch elements ============
// 512 thr (8 waves), grid 512 -> 2 blocks/CU -> 4 waves/SIMD (the occupancy doubling).
// LDS: xt 10KB + h 18KB + W ring 32KB = ~60KB -> 2 blocks co-resident (120KB < 160KB).
__global__ __launch_bounds__(512, 4) void cin_fused(const float* __restrict__ x,
                                                    const half_t* __restrict__ w0h,
                                                    const half_t* __restrict__ w1h,
                                                    const half_t* __restrict__ w2h,
                                                    const float* __restrict__ b0p,
                                                    const float* __restrict__ b1p,
                                                    const float* __restrict__ b2p,
                                                    float* __restrict__ out) {
  __shared__ __align__(16) half_t xt_lds[128 * XTP];
  __shared__ __align__(16) half_t h_lds[128 * HP];
  __shared__ __align__(16) half_t w_ring[4 * 4096];

  const int tid = threadIdx.x;
  const size_t b0 = (size_t)blockIdx.x * 8;
  const int phase = (blockIdx.x >> 3) & 3;     // co-XCD blocks start on different octets

  // ---- stage xt from x f32 (b,f,e) -> LDS (b,e) rows x 32 f, f16 ----
#pragma unroll
  for (int i = 0; i < 2; ++i) {
    int idx = (i * 512 + tid) * 4;             // 0..4095 by 4 (e%4==0 within one f,b)
    float4 v = *(const float4*)(x + b0 * 512 + idx);
    int e = idx & 15, f = (idx >> 4) & 31, b = idx >> 9;
    half_t* d = xt_lds + (b * 16 + e) * XTP + f;
    d[0 * XTP] = (half_t)v.x;
    d[1 * XTP] = (half_t)v.y;
    d[2 * XTP] = (half_t)v.z;
    d[3 * XTP] = (half_t)v.w;
  }

  // layer 0: G=32 (h = x0), keep o<64 -> out ch [0,64), o>=64 -> h_lds
  layer<32, 1024, 64, 0, true, true>(w0h, b0p, xt_lds, h_lds, w_ring, out, b0, tid, phase);
  // layer 1: G=64, keep o<64 -> out ch [64,128), o>=64 -> h_lds (overwrite)
  layer<64, 2048, 64, 64, true, false>(w1h, b1p, xt_lds, h_lds, w_ring, out, b0, tid, phase);
  // layer 2: G=64, keep all 128 -> out ch [128,256)
  layer<64, 2048, 128, 128, false, false>(w2h, b2p, xt_lds, h_lds, w_ring, out, b0, tid, phase);
}

extern "C" void kernel_launch(void* const* d_in, const int* in_sizes, int n_in,
                              void* d_out, int out_size, void* d_ws, size_t ws_size,
                              hipStream_t stream) {
  const float* x  = (const float*)d_in[0];
  const float* W0 = (const float*)d_in[1];
  const float* b0 = (const float*)d_in[2];
  const float* W1 = (const float*)d_in[3];
  const float* b1 = (const float*)d_in[4];
  const float* W2 = (const float*)d_in[5];
  const float* b2 = (const float*)d_in[6];
  float* out = (float*)d_out;
  char* ws = (char*)d_ws;

  half_t* w0h = (half_t*)(ws);                       // 256 KB
  half_t* w1h = (half_t*)(ws + (256u << 10));        // 512 KB
  half_t* w2h = (half_t*)(ws + (768u << 10));        // 512 KB

  prep_w_all<<<320, 256, 0, stream>>>(W0, W1, W2, w0h, w1h, w2h);
  cin_fused<<<512, 512, 0, stream>>>(x, w0h, w1h, w2h, b0, b1, b2, out);
}